// Round 1
// baseline (234.127 us; speedup 1.0000x reference)
//
#include <hip/hip_runtime.h>

#define RES 300
#define NC 8          // channels per plane
#define KF 24         // 3*NC features
#define AP 32         // output dim

// ---------------- prologue 1: planes [3,C,300,300] -> planesT [3,300,300,C] ----
__global__ __launch_bounds__(256) void transpose_planes(const float* __restrict__ planes,
                                                        float* __restrict__ planesT) {
    int idx = blockIdx.x * blockDim.x + threadIdx.x;   // over 3*RES*RES (y,x) slots
    if (idx >= 3 * RES * RES) return;
    int x = idx % RES;
    int t = idx / RES;
    int y = t % RES;
    int i = t / RES;
    float v[NC];
#pragma unroll
    for (int c = 0; c < NC; ++c)
        v[c] = planes[((i * NC + c) * RES + y) * RES + x];
    float4* dst = (float4*)(planesT + (size_t)idx * NC);
    dst[0] = make_float4(v[0], v[1], v[2], v[3]);
    dst[1] = make_float4(v[4], v[5], v[6], v[7]);
}

// ---------------- prologue 2: line table lt[3][300][8] = 0.5*(col149+col150) ---
__global__ __launch_bounds__(256) void build_lt(const float* __restrict__ planes,
                                                float* __restrict__ lt) {
    int idx = blockIdx.x * blockDim.x + threadIdx.x;   // over 3*RES*NC
    if (idx >= 3 * RES * NC) return;
    int c = idx % NC;
    int t = idx / NC;
    int y = t % RES;
    int i = t / RES;
    const float* row = planes + ((i * NC + c) * RES + y) * RES;
    lt[idx] = 0.5f * (row[149] + row[150]);
}

// 'size' is a Python scalar; harness may pass int32 or float32 bits.
__device__ __forceinline__ float decode_scalar(const void* p) {
    int b = *(const int*)p;
    if (b > 0 && b < (1 << 23)) return (float)b;   // small positive int
    return __int_as_float(b);                      // float bit pattern
}

// ---------------- main: sample + feature product + [24->32] projection --------
__global__ __launch_bounds__(256) void tensorf_main(
    const float* __restrict__ inputs, const float* __restrict__ W,
    const float* __restrict__ planesT, const float* __restrict__ lt,
    const void* __restrict__ size_p, float* __restrict__ out, int N)
{
    __shared__ float slt[3 * RES * NC];   // 28.8 KB line table
    for (int i = threadIdx.x; i < 3 * RES * NC; i += 256)
        slt[i] = lt[i];
    __syncthreads();

    int n = blockIdx.x * 256 + threadIdx.x;
    if (n >= N) return;

    float inv_s = 1.0f / decode_scalar(size_p);
    float c0 = inputs[3 * n + 0] * inv_s;
    float c1 = inputs[3 * n + 1] * inv_s;
    float c2 = inputs[3 * n + 2] * inv_s;

    // MAT_MODE = {(0,1),(0,2),(1,2)}  gx indexes W-dim, gy indexes H-dim
    // VEC_MODE = {2,1,0}
    float gx[3] = {c0, c0, c1};
    float gy[3] = {c1, c2, c2};
    float gv[3] = {c2, c1, c0};

    float feat[KF];

#pragma unroll
    for (int i = 0; i < 3; ++i) {
        float xx = (gx[i] + 1.0f) * (0.5f * (RES - 1));
        float yy = (gy[i] + 1.0f) * (0.5f * (RES - 1));
        float xf = fminf(fmaxf(floorf(xx), 0.0f), (float)(RES - 2));
        float yf = fminf(fmaxf(floorf(yy), 0.0f), (float)(RES - 2));
        int   x0 = (int)xf, y0 = (int)yf;
        float wx = xx - xf, wy = yy - yf;

        const float* b0 = planesT + ((size_t)((i * RES + y0) * RES + x0)) * NC;
        const float* b1 = b0 + RES * NC;
        float4 a0 = *(const float4*)(b0 + 0);
        float4 a1 = *(const float4*)(b0 + 4);
        float4 a2 = *(const float4*)(b0 + 8);
        float4 a3 = *(const float4*)(b0 + 12);
        float4 d0 = *(const float4*)(b1 + 0);
        float4 d1 = *(const float4*)(b1 + 4);
        float4 d2 = *(const float4*)(b1 + 8);
        float4 d3 = *(const float4*)(b1 + 12);

        float yv  = (gv[i] + 1.0f) * (0.5f * (RES - 1));
        float yvf = fminf(fmaxf(floorf(yv), 0.0f), (float)(RES - 2));
        int   y0v = (int)yvf;
        float wv  = yv - yvf;
        const float* l0 = slt + (i * RES + y0v) * NC;
        float4 e0 = *(const float4*)(l0 + 0);
        float4 e1 = *(const float4*)(l0 + 4);
        float4 f0 = *(const float4*)(l0 + NC + 0);
        float4 f1 = *(const float4*)(l0 + NC + 4);

        float r00[NC] = {a0.x, a0.y, a0.z, a0.w, a1.x, a1.y, a1.z, a1.w};
        float r01[NC] = {a2.x, a2.y, a2.z, a2.w, a3.x, a3.y, a3.z, a3.w};
        float r10[NC] = {d0.x, d0.y, d0.z, d0.w, d1.x, d1.y, d1.z, d1.w};
        float r11[NC] = {d2.x, d2.y, d2.z, d2.w, d3.x, d3.y, d3.z, d3.w};
        float lv0[NC] = {e0.x, e0.y, e0.z, e0.w, e1.x, e1.y, e1.z, e1.w};
        float lv1[NC] = {f0.x, f0.y, f0.z, f0.w, f1.x, f1.y, f1.z, f1.w};

#pragma unroll
        for (int c = 0; c < NC; ++c) {
            float top = r00[c] + wx * (r01[c] - r00[c]);
            float bot = r10[c] + wx * (r11[c] - r10[c]);
            float p   = top + wy * (bot - top);
            float l   = lv0[c] + wv * (lv1[c] - lv0[c]);
            feat[i * NC + c] = p * l;
        }
    }

    // out[n, a] = sum_k feat[k] * W[a, k]   — W access is thread-uniform -> s_load
    float4* o = (float4*)(out + (size_t)n * AP);
#pragma unroll
    for (int a4 = 0; a4 < AP / 4; ++a4) {
        float r[4];
#pragma unroll
        for (int j = 0; j < 4; ++j) {
            int a = a4 * 4 + j;
            float s = 0.0f;
#pragma unroll
            for (int k = 0; k < KF; ++k)
                s = fmaf(feat[k], W[a * KF + k], s);
            r[j] = s;
        }
        o[a4] = make_float4(r[0], r[1], r[2], r[3]);
    }
}

extern "C" void kernel_launch(void* const* d_in, const int* in_sizes, int n_in,
                              void* d_out, int out_size, void* d_ws, size_t ws_size,
                              hipStream_t stream) {
    const float* inputs = (const float*)d_in[0];
    const float* planes = (const float*)d_in[1];
    const float* W      = (const float*)d_in[2];
    const void*  size_p = d_in[3];
    float* out = (float*)d_out;
    int N = in_sizes[0] / 3;

    // workspace layout: planesT (2,160,000 f) | lt (7,200 f)  => ~8.67 MB
    float* planesT = (float*)d_ws;
    float* lt      = planesT + 3 * RES * RES * NC;

    int tpos = 3 * RES * RES;
    transpose_planes<<<(tpos + 255) / 256, 256, 0, stream>>>(planes, planesT);
    int lpos = 3 * RES * NC;
    build_lt<<<(lpos + 255) / 256, 256, 0, stream>>>(planes, lt);
    tensorf_main<<<(N + 255) / 256, 256, 0, stream>>>(inputs, W, planesT, lt,
                                                      size_p, out, N);
}